// Round 9
// baseline (328.343 us; speedup 1.0000x reference)
//
#include <hip/hip_runtime.h>
#include <stdint.h>

// SpottingLoss: B=2048 batches, N=64 slots, F=19 features.
// Two-phase greedy bipartite matching (lax.scan, length 64 each) then
// permuted YOLO-ish loss summed over ALL axes -> single float output.
//
// Exactness argument (verified absmax 0.0 rounds 0-7):
//  - alpha in {0,1}; v,h stay {0,1}; D2 = D1 * (0/1 masks). Dead columns are
//    ZEROED in the LDS D1 row when killed, so an unmasked argmax over the row
//    equals the reference's masked argmax (D1 > 0 strictly for live cols:
//    x,p ~ U[0,1) -> |x-p| < 1).
//  - Row argmax first-index ties: tournament tree over fixed positions, left
//    child always holds smaller original indices, right replaces left only if
//    STRICTLY greater -> (max value, first index). Bitwise = jnp.argmax.
//  - Column argmax: u64 key (val_bits<<6 | 63-row) via LDS atomicMax:
//    monotone in val (val>0), larger 63-row = smaller row = first index.
//  - Every column proposed by a live row is matched+killed IN THAT ROUND
//    (Bm = v*A*D2 nonzero exactly at proposers; C picks the max; E=1 there),
//    so a loser always rescans, and keys never need resetting within a
//    batch (live cols have never been written; stale keys on dead cols only
//    re-assert kills; hbits &= ~killed idempotent).
//  - Dead rows contribute only zeros downstream; early exit when
//    ballot(vlive)==0: remaining scan steps are no-ops. Unmatched rows keep
//    perm=0 == argmax of an all-zero Permut row.
//  - Intra-wave ordering: one wave's DS ops are processed in issue order
//    (relied on since R4, absmax 0); the compiler inserts lgkmcnt waits for
//    data dependences, and cannot reorder possibly-aliasing DS ops.
//
// Round-9 (= R8 resubmit, de-risked): R8 never ran (container failed twice;
// no counters). Only resource-class change R8 made vs every version that
// ran was 88KB static LDS/WG -> eliminated: WPB 4->2, NWG 192->384 (same
// 768 waves, same per-wave code, 44KB LDS/WG, 3 WGs/CU by LDS).
// Model (fits all 8 measured experiments): wall = wave-arrival ramp
// (~39.4 waves/us, counted in WAVES not WGs per R4) + per-batch life
// ~25us that never moved. Life was scratch/serial-chain argmax (R7
// VGPR=56: the asm pin forced D1r to SCRATCH; rescan = 64 scratch loads
// + 64-deep serial dependent max chain at ~1 resident wave/SIMD).
// Fix both terms: (1) D1 in LDS + 6-level ILP tournament + dead-column
// zeroing (no masks) + round-1 argmax fused into the build;
// (2) 768 waves, dynamic batch popping, next batch prefetched into regs
// during current matching. Predicted dispatch 22-32us (falsified >=45),
// VGPR ~120-150 (falsified ~60), LDS_Block_Size 44032.

#define NN 64
#define NF 19
#define NW (NN * NF)    // 1216 floats per (batch, tensor)
#define NW4 (NW / 4)    // 304 float4
#define WPB 2           // waves per workgroup (44KB LDS/WG)
#define NWG 384         // workgroups -> 768 waves
#define NWAVES (NWG * WPB)
typedef unsigned long long u64;

__global__ __launch_bounds__(WPB * 64, 1) void spotting_loss_kernel(
    const float* __restrict__ yt, const float* __restrict__ yp,
    float* __restrict__ ws, unsigned* __restrict__ ctr, int nbatch)
{
  const int wid = threadIdx.x >> 6;   // wave id in block
  const int i   = threadIdx.x & 63;   // lane = row index
  const int g   = blockIdx.x * WPB + wid;

  __shared__ float  d1s[WPB][NN][NN + 1];  // 64x65 f32 per wave (odd stride)
  __shared__ float4 yps4[WPB][NW4];
  __shared__ u64    key_lds[WPB][NN];
  const float* __restrict__ yps = (const float*)&yps4[wid][0];
  float* __restrict__ drow = &d1s[wid][i][0];
  u64* __restrict__ key_sh = &key_lds[wid][0];

  float lsum = 0.0f;

  // ---- prologue: pop first batch, prefetch its yp-stage + (alpha,x) ----
  unsigned bb;
  if (i == 0) bb = atomicAdd(ctr, 1u);
  bb = (unsigned)__shfl((int)bb, 0);

  const bool st4v = (i + 256) < NW4;  // 304 = 4*64 + 48
  float4 st0, st1, st2, st3, st4;
  float a_n = 0.0f, x_n = 0.0f;
  if (bb < (unsigned)nbatch) {
    const float4* yp4 = (const float4*)(yp + (size_t)bb * NW);
    st0 = yp4[i]; st1 = yp4[i + 64]; st2 = yp4[i + 128]; st3 = yp4[i + 192];
    if (st4v) st4 = yp4[i + 256];
    const float* ytr0 = yt + (size_t)bb * NW + (size_t)i * NF;
    a_n = ytr0[0]; x_n = ytr0[1];
  }

#pragma unroll 1
  while (bb < (unsigned)nbatch) {
    const int   b     = (int)bb;
    const float alpha = a_n;
    const float x     = x_n;

    // commit prefetched yp to this wave's LDS slice (in-order DS: after the
    // previous batch's loss reads, before this batch's build reads)
    yps4[wid][i]       = st0;
    yps4[wid][i + 64]  = st1;
    yps4[wid][i + 128] = st2;
    yps4[wid][i + 192] = st3;
    if (st4v) yps4[wid][i + 256] = st4;
    key_sh[i] = 63ull;  // per-batch init: (val=0,row=0); never reset again

    // pop + prefetch NEXT batch (hides under this batch's compute)
    unsigned bn;
    if (i == 0) bn = atomicAdd(ctr, 1u);
    bn = (unsigned)__shfl((int)bn, 0);
    if (bn < (unsigned)nbatch) {
      const float4* yp4n = (const float4*)(yp + (size_t)bn * NW);
      st0 = yp4n[i]; st1 = yp4n[i + 64]; st2 = yp4n[i + 128];
      st3 = yp4n[i + 192];
      if (st4v) st4 = yp4n[i + 256];
      const float* ytrn = yt + (size_t)bn * NW + (size_t)i * NF;
      a_n = ytrn[0]; x_n = ytrn[1];
    }

    // this batch's yt loss fields (per-lane 76B row; needed only at loss)
    const float* __restrict__ ytr = yt + (size_t)b * NW + (size_t)i * NF;
    float ytf[NF - 2];
#pragma unroll
    for (int f = 2; f < NF; ++f) ytf[f - 2] = ytr[f];

    // ---- D1 build into LDS + fused round-1 tournament (all cols live) ----
    unsigned bv;  int jmax;
    {
      unsigned v1[32]; int x1[32];
#pragma unroll
      for (int j = 0; j < 32; ++j) {
        const float da_ = 1.0f - fabsf(x - yps[(2 * j) * NF + 1]);
        const float db_ = 1.0f - fabsf(x - yps[(2 * j + 1) * NF + 1]);
        drow[2 * j]     = da_;
        drow[2 * j + 1] = db_;
        const unsigned ua = __float_as_uint(da_), ub = __float_as_uint(db_);
        const bool t = ub > ua;
        v1[j] = t ? ub : ua;  x1[j] = t ? (2 * j + 1) : (2 * j);
      }
      unsigned v2[16]; int x2[16];
#pragma unroll
      for (int j = 0; j < 16; ++j) { const bool t = v1[2*j+1] > v1[2*j]; v2[j] = t ? v1[2*j+1] : v1[2*j]; x2[j] = t ? x1[2*j+1] : x1[2*j]; }
      unsigned v3[8]; int x3[8];
#pragma unroll
      for (int j = 0; j < 8; ++j)  { const bool t = v2[2*j+1] > v2[2*j]; v3[j] = t ? v2[2*j+1] : v2[2*j]; x3[j] = t ? x2[2*j+1] : x2[2*j]; }
      unsigned v4[4]; int x4[4];
#pragma unroll
      for (int j = 0; j < 4; ++j)  { const bool t = v3[2*j+1] > v3[2*j]; v4[j] = t ? v3[2*j+1] : v3[2*j]; x4[j] = t ? x3[2*j+1] : x3[2*j]; }
      unsigned v5[2]; int x5[2];
#pragma unroll
      for (int j = 0; j < 2; ++j)  { const bool t = v4[2*j+1] > v4[2*j]; v5[j] = t ? v4[2*j+1] : v4[2*j]; x5[j] = t ? x4[2*j+1] : x4[2*j]; }
      const bool t = v5[1] > v5[0];
      bv = t ? v5[1] : v5[0];  jmax = t ? x5[1] : x5[0];
    }

    // ---- two-phase matching ----
    u64 hbits = ~0ull;  // column alive <=> bit set (wave-uniform)
    int perm  = 0;      // matched column (argmax of zero row -> 0)

#pragma unroll 1
    for (int phase = 0; phase < 2; ++phase) {
      bool vlive  = (phase == 0) ? (alpha > 0.5f) : (alpha < 0.5f);
      bool rescan = (phase == 1) && vlive;  // phase 0 uses the fused argmax

#pragma unroll 1
      for (int it = 0; it < NN; ++it) {
        if (__ballot(vlive) == 0ull) break;  // remaining steps are no-ops

        if (rescan) {
          // unmasked tournament over LDS row (dead cols are zeroed)
          unsigned w1[32]; int y1[32];
#pragma unroll
          for (int j = 0; j < 32; ++j) {
            const unsigned ua = __float_as_uint(drow[2 * j]);
            const unsigned ub = __float_as_uint(drow[2 * j + 1]);
            const bool t = ub > ua;
            w1[j] = t ? ub : ua;  y1[j] = t ? (2 * j + 1) : (2 * j);
          }
          unsigned w2[16]; int y2[16];
#pragma unroll
          for (int j = 0; j < 16; ++j) { const bool t = w1[2*j+1] > w1[2*j]; w2[j] = t ? w1[2*j+1] : w1[2*j]; y2[j] = t ? y1[2*j+1] : y1[2*j]; }
          unsigned w3[8]; int y3[8];
#pragma unroll
          for (int j = 0; j < 8; ++j)  { const bool t = w2[2*j+1] > w2[2*j]; w3[j] = t ? w2[2*j+1] : w2[2*j]; y3[j] = t ? y2[2*j+1] : y2[2*j]; }
          unsigned w4[4]; int y4[4];
#pragma unroll
          for (int j = 0; j < 4; ++j)  { const bool t = w3[2*j+1] > w3[2*j]; w4[j] = t ? w3[2*j+1] : w3[2*j]; y4[j] = t ? y3[2*j+1] : y3[2*j]; }
          unsigned w5[2]; int y5[2];
#pragma unroll
          for (int j = 0; j < 2; ++j)  { const bool t = w4[2*j+1] > w4[2*j]; w5[j] = t ? w4[2*j+1] : w4[2*j]; y5[j] = t ? y4[2*j+1] : y4[2*j]; }
          const bool t = w5[1] > w5[0];
          bv = t ? w5[1] : w5[0];  jmax = t ? y5[1] : y5[0];
          rescan = false;
        }

        if (vlive) {
          atomicMax(&key_sh[jmax], (((u64)bv) << 6) | (u64)(63 - i));
        }
        // same-wave DS in-order; possibly-aliasing DS ops keep program
        // order; compiler inserts the lgkmcnt waits for the data deps.
        const u64 kc = key_sh[i];
        u64 kw = 63ull;
        if (vlive) kw = key_sh[jmax];

        const u64 killed_new = __ballot((kc >> 6) != 0ull) & hbits;
        if (vlive) {
          if ((int)(kw & 63ull) == 63 - i) {  // mutual match
            perm  = jmax;
            vlive = false;
          } else {
            rescan = true;  // proposed column always dies -> always rescan
          }
        }
        // zero newly-killed columns in my D1 row (pre-masks future rescans)
        u64 t = killed_new;
        while (t) {
          const int c = __ffsll((long long)t) - 1;
          t &= t - 1;
          drow[c] = 0.0f;
        }
        hbits &= ~killed_new;
      }
    }

    // ----- loss: yp fields from LDS (perm gather), yt from regs -----
    const float* __restrict__ ypr = yps + perm * NF;
    const float a  = alpha;
    const float p0 = ypr[0];
    const float p1 = ypr[1];
    const float dx = x - p1;
    const float da = a - p0;
    float s2 = 0.0f;
#pragma unroll
    for (int f = 2; f < NF; ++f) {
      const float d = ytf[f - 2] - ypr[f];
      s2 += d * d;
    }
    lsum += a * 5.0f * (dx * dx)
          + a * (da * da)
          + (1.0f - a) * 0.5f * (da * da)
          + a * s2;

    bb = bn;
  }

  // wave-64 reduction of accumulated partials, one store per wave
#pragma unroll
  for (int off = 32; off > 0; off >>= 1) lsum += __shfl_down(lsum, off);
  if (i == 0) ws[g] = lsum;
}

__global__ __launch_bounds__(256) void reduce_ws_kernel(
    const float* __restrict__ ws, float* __restrict__ out, int nw)
{
  const int t = threadIdx.x;
  float s = 0.0f;
  for (int j = t; j < nw; j += 256) s += ws[j];
  __shared__ float part[4];
#pragma unroll
  for (int off = 32; off > 0; off >>= 1) s += __shfl_down(s, off);
  if ((t & 63) == 0) part[t >> 6] = s;
  __syncthreads();
  if (t == 0) out[0] = part[0] + part[1] + part[2] + part[3];
}

extern "C" void kernel_launch(void* const* d_in, const int* in_sizes, int n_in,
                              void* d_out, int out_size, void* d_ws, size_t ws_size,
                              hipStream_t stream) {
  const float* yt = (const float*)d_in[0];
  const float* yp = (const float*)d_in[1];
  float* out = (float*)d_out;
  float* ws  = (float*)d_ws;
  const int B = in_sizes[0] / (NN * NF);

  // ws layout: [0, NWAVES) partial sums; pop counter at ws[NWAVES]
  unsigned* ctr = (unsigned*)(ws + NWAVES);
  hipMemsetAsync(ctr, 0, sizeof(unsigned), stream);
  if (out_size > 1) {
    hipMemsetAsync(out, 0, sizeof(float) * (size_t)out_size, stream);
  }
  spotting_loss_kernel<<<NWG, WPB * 64, 0, stream>>>(yt, yp, ws, ctr, B);
  reduce_ws_kernel<<<1, 256, 0, stream>>>(ws, out, NWAVES);
}